// Round 1
// baseline (84.471 us; speedup 1.0000x reference)
//
#include <hip/hip_runtime.h>
#include <math.h>

// Fuzzy capsule routing, MI355X.
// Shapes: l (64,32,16,8,8) f32; g (64,20,16); weight (20,32,4,4); beta_a (20,1).
// V[n,k,m=(c*64+wh),v=(i*4+o)] = sum_j lp[n,c,wh,i,j] * w[k,c,j,o],
//   lp[n,c,wh,i,j] = l[n, c, i*4+j, wh]   (wh = w*8+h, contiguous last 64).
// 3 routing iters: rn=||V-g||^2; rd=sum_k 1/rn; r=(1/(rn*rd))^2;
//   g_new[k] = (sum_m r*V) / (sum_m r).
// sigma[n,k] = sum_m (r3/s3) * ||V-g3||^2  (r3 uses g2); a = sigmoid(beta - 0.5 ln sigma).
// Out: a flat (64*20=1280) then g flat (64*20*16=20480).

#define NB 64
#define NK 20
#define NC 32
#define NSPLIT 8
#define CPB 4              // channels per block = NC/NSPLIT

__device__ __forceinline__ float frcp(float x){ return __builtin_amdgcn_rcpf(x); }

// ---------------- routing iteration ----------------
template<int FIRST>
__global__ __launch_bounds__(256)
void k_route(const float* __restrict__ l, const float* __restrict__ wgt,
             const float* __restrict__ g_in, const float* __restrict__ Pprev,
             float* __restrict__ Pout)
{
    const int split = blockIdx.x;     // 0..7
    const int n     = blockIdx.y;     // 0..63
    const int tid   = threadIdx.x;    // 0..255
    const int c0    = split * CPB;

    __shared__ float wt_s[NK * 65];        // [k][cl*16 + j*4+o], pad 1/k -> odd stride
    __shared__ float lp_s[CPB * 16 * 64];  // [cl][dd][wh]
    __shared__ float r_s[NK * 257];        // [k][m_loc], pad -> stride 257
    __shared__ float g_s[NK * 16];
    __shared__ float tmp_s[NK * 17];
    __shared__ float red_s[8 * 32 * 17];

    // stage weights for this c-range: w[k, c0+cl, j, o]
    for (int t = tid; t < NK * 64; t += 256) {
        int k = t >> 6, rest = t & 63;
        wt_s[k * 65 + rest] = wgt[k * 512 + c0 * 16 + rest];
    }
    // stage lp chunk: 4096 consecutive floats of l
    const float* lsrc = l + ((size_t)n * NC + c0) * 1024;
    #pragma unroll
    for (int i = 0; i < 16; i++)
        lp_s[tid + i * 256] = lsrc[tid + i * 256];

    if (FIRST) {
        for (int t = tid; t < NK * 16; t += 256) g_s[t] = g_in[n * NK * 16 + t];
    } else {
        for (int t = tid; t < NK * 17; t += 256) {
            int k = t / 17, x = t % 17;
            float acc = 0.f;
            for (int s = 0; s < NSPLIT; s++)
                acc += Pprev[((n * NSPLIT + s) * NK + k) * 17 + x];
            tmp_s[t] = acc;
        }
        __syncthreads();
        for (int t = tid; t < NK * 16; t += 256) {
            int k = t >> 4, d = t & 15;
            g_s[t] = tmp_s[k * 17 + d] / tmp_s[k * 17 + 16];
        }
    }
    __syncthreads();

    // ---- phase 1: one m per thread, all k: r -> r_s ----
    {
        const int wh = tid & 63, cl = tid >> 6;
        float lpv[16];
        #pragma unroll
        for (int dd = 0; dd < 16; dd++) lpv[dd] = lp_s[cl * 1024 + dd * 64 + wh];

        float invs[NK];
        float rd = 0.f;
        #pragma unroll
        for (int k = 0; k < NK; k++) {
            const float* wt = &wt_s[k * 65 + cl * 16];
            float rn = 0.f;
            #pragma unroll
            for (int i = 0; i < 4; i++) {
                #pragma unroll
                for (int o = 0; o < 4; o++) {
                    float v = lpv[i*4+0] * wt[0+o] + lpv[i*4+1] * wt[4+o]
                            + lpv[i*4+2] * wt[8+o] + lpv[i*4+3] * wt[12+o];
                    float df = v - g_s[k * 16 + i * 4 + o];
                    rn += df * df;
                }
            }
            float inv = frcp(rn);
            invs[k] = inv;
            rd += inv;
        }
        float ird = frcp(rd);
        #pragma unroll
        for (int k = 0; k < NK; k++) {
            float t = invs[k] * ird;
            r_s[k * 257 + tid] = t * t;
        }
    }
    __syncthreads();

    // ---- phase 3: thread = (k, mi); accumulate s, u[16] privately ----
    const int k3 = tid & 31, mi = tid >> 5;
    float uacc[16];
    float sacc = 0.f;
    #pragma unroll
    for (int d = 0; d < 16; d++) uacc[d] = 0.f;

    if (k3 < NK) {
        const int cl3 = mi >> 1;                  // constant: 32 m stay in one c
        float wtr[16];
        #pragma unroll
        for (int x = 0; x < 16; x++) wtr[x] = wt_s[k3 * 65 + cl3 * 16 + x];
        for (int j = 0; j < 32; j++) {
            int m = mi * 32 + j;
            int whm = m & 63;
            float lv[16];
            #pragma unroll
            for (int dd = 0; dd < 16; dd++) lv[dd] = lp_s[cl3 * 1024 + dd * 64 + whm];
            float r = r_s[k3 * 257 + m];
            sacc += r;
            #pragma unroll
            for (int i = 0; i < 4; i++) {
                #pragma unroll
                for (int o = 0; o < 4; o++) {
                    float v = lv[i*4+0] * wtr[0+o] + lv[i*4+1] * wtr[4+o]
                            + lv[i*4+2] * wtr[8+o] + lv[i*4+3] * wtr[12+o];
                    uacc[i * 4 + o] += r * v;
                }
            }
        }
    }
    #pragma unroll
    for (int d = 0; d < 16; d++) red_s[tid * 17 + d] = uacc[d];
    red_s[tid * 17 + 16] = sacc;
    __syncthreads();

    for (int t = tid; t < NK * 17; t += 256) {
        int k = t / 17, x = t % 17;
        float acc = 0.f;
        #pragma unroll
        for (int m2 = 0; m2 < 8; m2++) acc += red_s[(m2 * 32 + k) * 17 + x];
        Pout[((n * NSPLIT + split) * NK + k) * 17 + x] = acc;
    }
}

// ---------------- sigma pass ----------------
__global__ __launch_bounds__(256)
void k_sigma(const float* __restrict__ l, const float* __restrict__ wgt,
             const float* __restrict__ P2, const float* __restrict__ P3,
             float* __restrict__ PS)
{
    const int split = blockIdx.x;
    const int n     = blockIdx.y;
    const int tid   = threadIdx.x;
    const int c0    = split * CPB;

    __shared__ float wt_s[NK * 65];
    __shared__ float lp_s[CPB * 16 * 64];
    __shared__ float r_s[NK * 257];
    __shared__ float g2_s[NK * 16];
    __shared__ float g3_s[NK * 16];
    __shared__ float is3_s[NK];
    __shared__ float tmp_s[NK * 17];
    __shared__ float red2_s[256];

    for (int t = tid; t < NK * 64; t += 256) {
        int k = t >> 6, rest = t & 63;
        wt_s[k * 65 + rest] = wgt[k * 512 + c0 * 16 + rest];
    }
    const float* lsrc = l + ((size_t)n * NC + c0) * 1024;
    #pragma unroll
    for (int i = 0; i < 16; i++)
        lp_s[tid + i * 256] = lsrc[tid + i * 256];

    // g2 from P2
    for (int t = tid; t < NK * 17; t += 256) {
        int k = t / 17, x = t % 17;
        float acc = 0.f;
        for (int s = 0; s < NSPLIT; s++) acc += P2[((n * NSPLIT + s) * NK + k) * 17 + x];
        tmp_s[t] = acc;
    }
    __syncthreads();
    for (int t = tid; t < NK * 16; t += 256) {
        int k = t >> 4, d = t & 15;
        g2_s[t] = tmp_s[k * 17 + d] / tmp_s[k * 17 + 16];
    }
    __syncthreads();
    // g3, s3 from P3
    for (int t = tid; t < NK * 17; t += 256) {
        int k = t / 17, x = t % 17;
        float acc = 0.f;
        for (int s = 0; s < NSPLIT; s++) acc += P3[((n * NSPLIT + s) * NK + k) * 17 + x];
        tmp_s[t] = acc;
    }
    __syncthreads();
    for (int t = tid; t < NK * 16; t += 256) {
        int k = t >> 4, d = t & 15;
        g3_s[t] = tmp_s[k * 17 + d] / tmp_s[k * 17 + 16];
    }
    if (tid < NK) is3_s[tid] = 1.f / tmp_s[tid * 17 + 16];
    __syncthreads();

    // phase 1: r (w.r.t. g2)
    {
        const int wh = tid & 63, cl = tid >> 6;
        float lpv[16];
        #pragma unroll
        for (int dd = 0; dd < 16; dd++) lpv[dd] = lp_s[cl * 1024 + dd * 64 + wh];
        float invs[NK];
        float rd = 0.f;
        #pragma unroll
        for (int k = 0; k < NK; k++) {
            const float* wt = &wt_s[k * 65 + cl * 16];
            float rn = 0.f;
            #pragma unroll
            for (int i = 0; i < 4; i++) {
                #pragma unroll
                for (int o = 0; o < 4; o++) {
                    float v = lpv[i*4+0] * wt[0+o] + lpv[i*4+1] * wt[4+o]
                            + lpv[i*4+2] * wt[8+o] + lpv[i*4+3] * wt[12+o];
                    float df = v - g2_s[k * 16 + i * 4 + o];
                    rn += df * df;
                }
            }
            float inv = frcp(rn);
            invs[k] = inv;
            rd += inv;
        }
        float ird = frcp(rd);
        #pragma unroll
        for (int k = 0; k < NK; k++) {
            float t = invs[k] * ird;
            r_s[k * 257 + tid] = t * t;
        }
    }
    __syncthreads();

    // phase 3: sigma partial: sum_m (r/s3) * ||V-g3||^2
    const int k3 = tid & 31, mi = tid >> 5;
    float sig = 0.f;
    if (k3 < NK) {
        const int cl3 = mi >> 1;
        float wtr[16], gr[16];
        #pragma unroll
        for (int x = 0; x < 16; x++) wtr[x] = wt_s[k3 * 65 + cl3 * 16 + x];
        #pragma unroll
        for (int d = 0; d < 16; d++) gr[d] = g3_s[k3 * 16 + d];
        for (int j = 0; j < 32; j++) {
            int m = mi * 32 + j;
            int whm = m & 63;
            float lv[16];
            #pragma unroll
            for (int dd = 0; dd < 16; dd++) lv[dd] = lp_s[cl3 * 1024 + dd * 64 + whm];
            float r = r_s[k3 * 257 + m];
            float dist = 0.f;
            #pragma unroll
            for (int i = 0; i < 4; i++) {
                #pragma unroll
                for (int o = 0; o < 4; o++) {
                    float v = lv[i*4+0] * wtr[0+o] + lv[i*4+1] * wtr[4+o]
                            + lv[i*4+2] * wtr[8+o] + lv[i*4+3] * wtr[12+o];
                    float df = v - gr[i * 4 + o];
                    dist += df * df;
                }
            }
            sig += r * dist;
        }
        sig *= is3_s[k3];
    }
    red2_s[tid] = sig;
    __syncthreads();
    if (tid < NK) {
        float acc = 0.f;
        #pragma unroll
        for (int m2 = 0; m2 < 8; m2++) acc += red2_s[m2 * 32 + tid];
        PS[(n * NSPLIT + split) * NK + tid] = acc;
    }
}

// ---------------- finalize ----------------
__global__ __launch_bounds__(512)
void k_final(const float* __restrict__ P3, const float* __restrict__ PS,
             const float* __restrict__ beta, float* __restrict__ out)
{
    const int n = blockIdx.x, tid = threadIdx.x;
    __shared__ float tmp_s[NK * 17];
    __shared__ float sig_s[NK];
    for (int t = tid; t < NK * 17; t += 512) {
        int k = t / 17, x = t % 17;
        float acc = 0.f;
        for (int s = 0; s < NSPLIT; s++) acc += P3[((n * NSPLIT + s) * NK + k) * 17 + x];
        tmp_s[t] = acc;
    }
    if (tid < NK) {
        float acc = 0.f;
        for (int s = 0; s < NSPLIT; s++) acc += PS[(n * NSPLIT + s) * NK + tid];
        sig_s[tid] = acc;
    }
    __syncthreads();
    if (tid < NK * 16) {
        int k = tid >> 4;
        out[1280 + n * 320 + tid] = tmp_s[k * 17 + (tid & 15)] / tmp_s[k * 17 + 16];
    }
    if (tid < NK) {
        float z = beta[tid] - 0.5f * logf(sig_s[tid]);   // LAMBDA = 1
        out[n * NK + tid] = 1.f / (1.f + expf(-z));
    }
}

extern "C" void kernel_launch(void* const* d_in, const int* in_sizes, int n_in,
                              void* d_out, int out_size, void* d_ws, size_t ws_size,
                              hipStream_t stream)
{
    const float* l    = (const float*)d_in[0];
    const float* g    = (const float*)d_in[1];
    const float* wgt  = (const float*)d_in[2];
    const float* beta = (const float*)d_in[3];
    float* out = (float*)d_out;

    const size_t PSZ = (size_t)NB * NSPLIT * NK * 17;   // 174080 floats
    float* P1 = (float*)d_ws;
    float* P2 = P1 + PSZ;
    float* P3 = P2 + PSZ;
    float* PS = P3 + PSZ;                               // 64*8*20 floats

    dim3 grid(NSPLIT, NB), blk(256);
    k_route<1><<<grid, blk, 0, stream>>>(l, wgt, g, nullptr, P1);
    k_route<0><<<grid, blk, 0, stream>>>(l, wgt, nullptr, P1, P2);
    k_route<0><<<grid, blk, 0, stream>>>(l, wgt, nullptr, P2, P3);
    k_sigma<<<grid, blk, 0, stream>>>(l, wgt, P2, P3, PS);
    k_final<<<NB, 512, 0, stream>>>(P3, PS, beta, out);
}

// Round 2
// 59.434 us; speedup vs baseline: 1.4213x; 1.4213x over previous
//
#include <hip/hip_runtime.h>
#include <math.h>

// Fuzzy capsule routing, MI355X — round 2: algebraic restructuring.
// rn = ||V||^2 - 2<V,g> + ||g||^2 with per-m outer products QS (k-independent)
// and per-(k,c) precomputed M~ = mult*W W^T, wg2 = -2 W g, cst = ||g||^2.
// Phase 3 accumulates T[k,c,ij] = sum_wh r*lp and contracts with W at the end.

#define NB 64
#define NK 20
#define NSPLIT 8
#define CPB 4
#define LPST 20           // lp row stride (floats), 16B-aligned, bank-spread
#define MWR_R 32          // mw row stride (route)
#define MWR_S 44          // mw row stride (sigma; +cst3 at 27, wg3 at 28..43)

__device__ __forceinline__ float frcp(float x){ return __builtin_amdgcn_rcpf(x); }

// ---- per-(cl,k) coefficient build: one thread each, tid<80 ----
// row layout: [0..15] wg2 (idx i*4+j), [16..25] M~ pairs
// {(0,0),(0,1),(0,2),(0,3),(1,1),(1,2),(1,3),(2,2),(2,3),(3,3)}, [26] ||gA||^2
// DUAL: [27] ||gB||^2, [28..43] wg2 from gB.
template<int ROW, int DUAL>
__device__ __forceinline__ void build_mw(float* mw_s, const float* wt_s,
                                         const float* gA_s, const float* gB_s, int tid)
{
    if (tid < 4*NK) {
        const int cl = tid / NK, k = tid % NK;
        float w[16], ga[16];
        #pragma unroll
        for (int x=0;x<16;x++) w[x] = wt_s[k*65 + cl*16 + x];
        #pragma unroll
        for (int x=0;x<16;x++) ga[x] = gA_s[k*16 + x];
        float* row = &mw_s[(cl*NK + k)*ROW];
        #pragma unroll
        for (int i=0;i<4;i++)
            #pragma unroll
            for (int j=0;j<4;j++){
                float a = w[j*4+0]*ga[i*4+0] + w[j*4+1]*ga[i*4+1]
                        + w[j*4+2]*ga[i*4+2] + w[j*4+3]*ga[i*4+3];
                row[i*4+j] = -2.f*a;
            }
        {
            int p = 0;
            #pragma unroll
            for (int j=0;j<4;j++)
                #pragma unroll
                for (int jp=j;jp<4;jp++){
                    float a = w[j*4+0]*w[jp*4+0] + w[j*4+1]*w[jp*4+1]
                            + w[j*4+2]*w[jp*4+2] + w[j*4+3]*w[jp*4+3];
                    row[16+p] = (j==jp)? a : 2.f*a;
                    p++;
                }
        }
        float c = 0.f;
        #pragma unroll
        for (int x=0;x<16;x++) c += ga[x]*ga[x];
        row[26] = c;
        if (DUAL) {
            float gb[16];
            #pragma unroll
            for (int x=0;x<16;x++) gb[x] = gB_s[k*16 + x];
            #pragma unroll
            for (int i=0;i<4;i++)
                #pragma unroll
                for (int j=0;j<4;j++){
                    float a = w[j*4+0]*gb[i*4+0] + w[j*4+1]*gb[i*4+1]
                            + w[j*4+2]*gb[i*4+2] + w[j*4+3]*gb[i*4+3];
                    row[28 + i*4+j] = -2.f*a;
                }
            float cb = 0.f;
            #pragma unroll
            for (int x=0;x<16;x++) cb += gb[x]*gb[x];
            row[27] = cb;
        }
    }
}

// ---- phase 1: thread per m; writes r_s[k][m] (and optionally QS) ----
template<int ROW, int STORE_QS>
__device__ __forceinline__ void phase1(const float* lp_s, const float* mw_s,
                                       float* r_s, float* qs_s, int tid)
{
    const int cl = tid >> 6, wh = tid & 63;
    const float* lpr = &lp_s[(cl*64 + wh)*LPST];
    float lp[16];
    #pragma unroll
    for (int q=0;q<4;q++){
        float4 v = *(const float4*)&lpr[q*4];
        lp[q*4+0]=v.x; lp[q*4+1]=v.y; lp[q*4+2]=v.z; lp[q*4+3]=v.w;
    }
    float QS[10];
    {
        int p=0;
        #pragma unroll
        for (int j=0;j<4;j++)
            #pragma unroll
            for (int jp=j;jp<4;jp++){
                QS[p] = lp[j]*lp[jp] + lp[4+j]*lp[4+jp]
                      + lp[8+j]*lp[8+jp] + lp[12+j]*lp[12+jp];
                p++;
            }
    }
    if (STORE_QS){
        *(float4*)&qs_s[tid*12+0] = make_float4(QS[0],QS[1],QS[2],QS[3]);
        *(float4*)&qs_s[tid*12+4] = make_float4(QS[4],QS[5],QS[6],QS[7]);
        *(float2*)&qs_s[tid*12+8] = make_float2(QS[8],QS[9]);
    }
    float invs[NK];
    float rd = 0.f;
    const float* base = &mw_s[cl*NK*ROW];
    #pragma unroll
    for (int k=0;k<NK;k++){
        const float* row = base + k*ROW;
        float4 w0 = *(const float4*)&row[0];
        float4 w1 = *(const float4*)&row[4];
        float4 w2 = *(const float4*)&row[8];
        float4 w3 = *(const float4*)&row[12];
        float4 m0 = *(const float4*)&row[16];
        float4 m1 = *(const float4*)&row[20];
        float2 m2 = *(const float2*)&row[24];
        float rn = row[26];
        rn += m0.x*QS[0] + m0.y*QS[1] + m0.z*QS[2] + m0.w*QS[3]
            + m1.x*QS[4] + m1.y*QS[5] + m1.z*QS[6] + m1.w*QS[7]
            + m2.x*QS[8] + m2.y*QS[9];
        rn += w0.x*lp[0] + w0.y*lp[1] + w0.z*lp[2] + w0.w*lp[3]
            + w1.x*lp[4] + w1.y*lp[5] + w1.z*lp[6] + w1.w*lp[7]
            + w2.x*lp[8] + w2.y*lp[9] + w2.z*lp[10]+ w2.w*lp[11]
            + w3.x*lp[12]+ w3.y*lp[13]+ w3.z*lp[14]+ w3.w*lp[15];
        float inv = frcp(rn);
        invs[k] = inv;
        rd += inv;
    }
    float ird = frcp(rd);
    #pragma unroll
    for (int k=0;k<NK;k++){
        float t = invs[k]*ird;
        r_s[k*257 + tid] = t*t;
    }
}

__device__ __forceinline__ void reduce_g(const float* __restrict__ P, int n,
                                         float* tmp_s, float* g_s, int tid)
{
    for (int t = tid; t < NK*17; t += 256){
        int k = t/17, x = t%17;
        float acc = 0.f;
        #pragma unroll
        for (int s=0;s<NSPLIT;s++) acc += P[((n*NSPLIT+s)*NK + k)*17 + x];
        tmp_s[t] = acc;
    }
    __syncthreads();
    for (int t = tid; t < NK*16; t += 256){
        int k = t>>4, d = t&15;
        g_s[t] = tmp_s[k*17 + d] / tmp_s[k*17 + 16];
    }
}

// ---------------- routing iteration ----------------
template<int FIRST>
__global__ __launch_bounds__(256)
void k_route(const float* __restrict__ l, const float* __restrict__ wgt,
             const float* __restrict__ g_in, const float* __restrict__ Pprev,
             float* __restrict__ Pout)
{
    const int split = blockIdx.x, n = blockIdx.y, tid = threadIdx.x;
    const int c0 = split*CPB;

    __shared__ float lp_s[CPB*64*LPST];    // 5120
    __shared__ float mw_s[CPB*NK*MWR_R];   // 2560
    __shared__ float wt_s[NK*65];          // 1300
    __shared__ float r_s[NK*257];          // 5140
    __shared__ float red_s[4*NK*17];       // 1360
    __shared__ float g_s[NK*16];
    __shared__ float tmp_s[NK*17];

    for (int t = tid; t < NK*64; t += 256){
        int k = t>>6, rest = t&63;
        wt_s[k*65 + rest] = wgt[k*512 + c0*16 + rest];
    }
    const float* lsrc = l + ((size_t)n*32 + c0)*1024;
    #pragma unroll
    for (int i=0;i<16;i++){
        int t = i*256 + tid;
        int cl = t>>10, dd = (t>>6)&15, wh = t&63;
        lp_s[(cl*64 + wh)*LPST + dd] = lsrc[t];
    }
    if (FIRST){
        for (int t=tid;t<NK*16;t+=256) g_s[t] = g_in[n*NK*16 + t];
        __syncthreads();
    } else {
        reduce_g(Pprev, n, tmp_s, g_s, tid);
        __syncthreads();
    }
    build_mw<MWR_R,0>(mw_s, wt_s, g_s, nullptr, tid);
    __syncthreads();
    phase1<MWR_R,0>(lp_s, mw_s, r_s, nullptr, tid);
    __syncthreads();

    // ---- phase 3: T[k,cl,ij] = sum_m r*lp ----
    const int k3 = tid & 31, mi = tid >> 5, cl3 = mi >> 1;
    const int kk = (k3 < NK)? k3 : NK-1;
    const float* lpb = &lp_s[cl3*64*LPST];
    float T[16]; float sacc = 0.f;
    #pragma unroll
    for (int d=0;d<16;d++) T[d]=0.f;
    #pragma unroll 4
    for (int j=0;j<32;j++){
        int m = mi*32 + j, wh = m & 63;
        float r = r_s[kk*257 + m];
        r = (k3 < NK)? r : 0.f;
        const float* lr = &lpb[wh*LPST];
        #pragma unroll
        for (int q=0;q<4;q++){
            float4 v = *(const float4*)&lr[q*4];
            T[q*4+0] += r*v.x; T[q*4+1] += r*v.y;
            T[q*4+2] += r*v.z; T[q*4+3] += r*v.w;
        }
        sacc += r;
    }
    #pragma unroll
    for (int d=0;d<16;d++) T[d] += __shfl_xor(T[d], 32, 64);
    sacc += __shfl_xor(sacc, 32, 64);
    if ((k3 < NK) && !(tid & 32)){
        float* row = &red_s[(cl3*NK + k3)*17];
        #pragma unroll
        for (int d=0;d<16;d++) row[d] = T[d];
        row[16] = sacc;
    }
    __syncthreads();

    // ---- final: u[k,io] = sum_cl sum_j T[k,cl,ij] w[k,cl,j,o]; s ----
    for (int t = tid; t < NK*17; t += 256){
        int k = t/17, x = t%17;
        float acc = 0.f;
        if (x == 16){
            #pragma unroll
            for (int cl=0;cl<4;cl++) acc += red_s[(cl*NK+k)*17 + 16];
        } else {
            int i = x>>2, o = x&3;
            #pragma unroll
            for (int cl=0;cl<4;cl++)
                #pragma unroll
                for (int j=0;j<4;j++)
                    acc += red_s[(cl*NK+k)*17 + i*4+j] * wt_s[k*65 + cl*16 + j*4+o];
        }
        Pout[((n*NSPLIT+split)*NK + k)*17 + x] = acc;
    }
}

// ---------------- sigma pass ----------------
__global__ __launch_bounds__(256)
void k_sigma(const float* __restrict__ l, const float* __restrict__ wgt,
             const float* __restrict__ P2, const float* __restrict__ P3,
             float* __restrict__ PS)
{
    const int split = blockIdx.x, n = blockIdx.y, tid = threadIdx.x;
    const int c0 = split*CPB;

    __shared__ float lp_s[CPB*64*LPST];    // 5120
    __shared__ float mw_s[CPB*NK*MWR_S];   // 3520
    __shared__ float wt_s[NK*65];          // 1300
    __shared__ float r_s[NK*257];          // 5140
    __shared__ float qs_s[256*12];         // 3072
    __shared__ float g2_s[NK*16], g3_s[NK*16];
    __shared__ float tmp_s[NK*17];
    __shared__ float is3_s[NK];
    __shared__ float red2_s[4*NK];

    for (int t = tid; t < NK*64; t += 256){
        int k = t>>6, rest = t&63;
        wt_s[k*65 + rest] = wgt[k*512 + c0*16 + rest];
    }
    const float* lsrc = l + ((size_t)n*32 + c0)*1024;
    #pragma unroll
    for (int i=0;i<16;i++){
        int t = i*256 + tid;
        int cl = t>>10, dd = (t>>6)&15, wh = t&63;
        lp_s[(cl*64 + wh)*LPST + dd] = lsrc[t];
    }
    reduce_g(P2, n, tmp_s, g2_s, tid);
    __syncthreads();
    reduce_g(P3, n, tmp_s, g3_s, tid);
    if (tid < NK) is3_s[tid] = 1.f / tmp_s[tid*17 + 16];
    __syncthreads();
    build_mw<MWR_S,1>(mw_s, wt_s, g2_s, g3_s, tid);
    __syncthreads();
    phase1<MWR_S,1>(lp_s, mw_s, r_s, qs_s, tid);
    __syncthreads();

    // ---- phase 3: sig[k] = sum_m r * (cst3 + M~.QS + wg3.lp) ----
    const int k3 = tid & 31, mi = tid >> 5, cl3 = mi >> 1;
    const int kk = (k3 < NK)? k3 : NK-1;
    const float* row = &mw_s[(cl3*NK + kk)*MWR_S];
    float Mt[10], wg3[16], c3;
    {
        float4 a0 = *(const float4*)&row[16];
        float4 a1 = *(const float4*)&row[20];
        float2 a2 = *(const float2*)&row[24];
        Mt[0]=a0.x; Mt[1]=a0.y; Mt[2]=a0.z; Mt[3]=a0.w;
        Mt[4]=a1.x; Mt[5]=a1.y; Mt[6]=a1.z; Mt[7]=a1.w;
        Mt[8]=a2.x; Mt[9]=a2.y;
        #pragma unroll
        for (int q=0;q<4;q++){
            float4 v = *(const float4*)&row[28 + q*4];
            wg3[q*4+0]=v.x; wg3[q*4+1]=v.y; wg3[q*4+2]=v.z; wg3[q*4+3]=v.w;
        }
        c3 = row[27];
    }
    const float* lpb = &lp_s[cl3*64*LPST];
    float sig = 0.f;
    #pragma unroll 4
    for (int j=0;j<32;j++){
        int m = mi*32 + j, wh = m & 63;
        float r = r_s[kk*257 + m];
        r = (k3 < NK)? r : 0.f;
        const float* qsr = &qs_s[m*12];
        float4 q0 = *(const float4*)&qsr[0];
        float4 q1 = *(const float4*)&qsr[4];
        float2 q2 = *(const float2*)&qsr[8];
        float rn = c3;
        rn += Mt[0]*q0.x + Mt[1]*q0.y + Mt[2]*q0.z + Mt[3]*q0.w
            + Mt[4]*q1.x + Mt[5]*q1.y + Mt[6]*q1.z + Mt[7]*q1.w
            + Mt[8]*q2.x + Mt[9]*q2.y;
        const float* lr = &lpb[wh*LPST];
        #pragma unroll
        for (int q=0;q<4;q++){
            float4 v = *(const float4*)&lr[q*4];
            rn += wg3[q*4+0]*v.x + wg3[q*4+1]*v.y + wg3[q*4+2]*v.z + wg3[q*4+3]*v.w;
        }
        sig += r*rn;
    }
    sig += __shfl_xor(sig, 32, 64);
    if ((k3 < NK) && !(tid & 32)) red2_s[cl3*NK + k3] = sig;
    __syncthreads();
    if (tid < NK){
        float acc = red2_s[tid] + red2_s[NK+tid] + red2_s[2*NK+tid] + red2_s[3*NK+tid];
        PS[(n*NSPLIT+split)*NK + tid] = acc * is3_s[tid];
    }
}

// ---------------- finalize ----------------
__global__ __launch_bounds__(512)
void k_final(const float* __restrict__ P3, const float* __restrict__ PS,
             const float* __restrict__ beta, float* __restrict__ out)
{
    const int n = blockIdx.x, tid = threadIdx.x;
    __shared__ float tmp_s[NK*17];
    __shared__ float sig_s[NK];
    for (int t = tid; t < NK*17; t += 512){
        int k = t/17, x = t%17;
        float acc = 0.f;
        #pragma unroll
        for (int s=0;s<NSPLIT;s++) acc += P3[((n*NSPLIT+s)*NK + k)*17 + x];
        tmp_s[t] = acc;
    }
    if (tid < NK){
        float acc = 0.f;
        #pragma unroll
        for (int s=0;s<NSPLIT;s++) acc += PS[(n*NSPLIT+s)*NK + tid];
        sig_s[tid] = acc;
    }
    __syncthreads();
    if (tid < NK*16){
        int k = tid >> 4;
        out[1280 + n*320 + tid] = tmp_s[k*17 + (tid&15)] / tmp_s[k*17 + 16];
    }
    if (tid < NK){
        float z = beta[tid] - 0.5f*logf(sig_s[tid]);   // LAMBDA = 1
        out[n*NK + tid] = 1.f/(1.f + expf(-z));
    }
}

extern "C" void kernel_launch(void* const* d_in, const int* in_sizes, int n_in,
                              void* d_out, int out_size, void* d_ws, size_t ws_size,
                              hipStream_t stream)
{
    const float* l    = (const float*)d_in[0];
    const float* g    = (const float*)d_in[1];
    const float* wgt  = (const float*)d_in[2];
    const float* beta = (const float*)d_in[3];
    float* out = (float*)d_out;

    const size_t PSZ = (size_t)NB * NSPLIT * NK * 17;
    float* P1 = (float*)d_ws;
    float* P2 = P1 + PSZ;
    float* P3 = P2 + PSZ;
    float* PS = P3 + PSZ;

    dim3 grid(NSPLIT, NB), blk(256);
    k_route<1><<<grid, blk, 0, stream>>>(l, wgt, g, nullptr, P1);
    k_route<0><<<grid, blk, 0, stream>>>(l, wgt, nullptr, P1, P2);
    k_route<0><<<grid, blk, 0, stream>>>(l, wgt, nullptr, P2, P3);
    k_sigma<<<grid, blk, 0, stream>>>(l, wgt, P2, P3, PS);
    k_final<<<NB, 512, 0, stream>>>(P3, PS, beta, out);
}

// Round 4
// 58.756 us; speedup vs baseline: 1.4377x; 1.0115x over previous
//
#include <hip/hip_runtime.h>
#include <math.h>

// Fuzzy capsule routing, MI355X — round 3 (resubmit after infra failure):
// occupancy (1024 blocks, CPB=2), k-split phase 1, float4 r reads in phase 3.

#define NB 64
#define NK 20
#define NSPLIT 16
#define CPB 2
#define LPST 20           // lp row stride
#define RST 132           // r_s row stride (16B aligned)
#define MWR_R 28
#define MWR_S 44

__device__ __forceinline__ float frcp(float x){ return __builtin_amdgcn_rcpf(x); }

// row: [0..15] wg2=-2Wg (i*4+j), [16..25] M~ pairs, [26] ||gA||^2
// DUAL: [27] ||gB||^2, [28..43] -2WgB.
template<int ROW, int DUAL>
__device__ __forceinline__ void build_mw(float* mw_s, const float* wt_s,
                                         const float* gA_s, const float* gB_s, int tid)
{
    if (tid < CPB*NK) {
        const int cl = tid / NK, k = tid % NK;
        float w[16], ga[16];
        #pragma unroll
        for (int x=0;x<16;x++) w[x] = wt_s[k*33 + cl*16 + x];
        #pragma unroll
        for (int x=0;x<16;x++) ga[x] = gA_s[k*16 + x];
        float* row = &mw_s[(cl*NK + k)*ROW];
        #pragma unroll
        for (int i=0;i<4;i++)
            #pragma unroll
            for (int j=0;j<4;j++){
                float a = w[j*4+0]*ga[i*4+0] + w[j*4+1]*ga[i*4+1]
                        + w[j*4+2]*ga[i*4+2] + w[j*4+3]*ga[i*4+3];
                row[i*4+j] = -2.f*a;
            }
        {
            int p = 0;
            #pragma unroll
            for (int j=0;j<4;j++)
                #pragma unroll
                for (int jp=j;jp<4;jp++){
                    float a = w[j*4+0]*w[jp*4+0] + w[j*4+1]*w[jp*4+1]
                            + w[j*4+2]*w[jp*4+2] + w[j*4+3]*w[jp*4+3];
                    row[16+p] = (j==jp)? a : 2.f*a;
                    p++;
                }
        }
        float c = 0.f;
        #pragma unroll
        for (int x=0;x<16;x++) c += ga[x]*ga[x];
        row[26] = c;
        if (DUAL) {
            float gb[16];
            #pragma unroll
            for (int x=0;x<16;x++) gb[x] = gB_s[k*16 + x];
            #pragma unroll
            for (int i=0;i<4;i++)
                #pragma unroll
                for (int j=0;j<4;j++){
                    float a = w[j*4+0]*gb[i*4+0] + w[j*4+1]*gb[i*4+1]
                            + w[j*4+2]*gb[i*4+2] + w[j*4+3]*gb[i*4+3];
                    row[28 + i*4+j] = -2.f*a;
                }
            float cb = 0.f;
            #pragma unroll
            for (int x=0;x<16;x++) cb += gb[x]*gb[x];
            row[27] = cb;
        }
    }
}

// phase 1: thread=(m, khalf); each does 10 k; rd combined via shfl_xor(1).
template<int ROW, int STORE_QS>
__device__ __forceinline__ void phase1(const float* lp_s, const float* mw_s,
                                       float* r_s, float* qs_s, int tid)
{
    const int m = tid >> 1, kh = tid & 1;
    const float* lpr = &lp_s[m*LPST];
    float lp[16];
    #pragma unroll
    for (int q=0;q<4;q++){
        float4 v = *(const float4*)&lpr[q*4];
        lp[q*4+0]=v.x; lp[q*4+1]=v.y; lp[q*4+2]=v.z; lp[q*4+3]=v.w;
    }
    float QS[10];
    {
        int p=0;
        #pragma unroll
        for (int j=0;j<4;j++)
            #pragma unroll
            for (int jp=j;jp<4;jp++){
                QS[p] = lp[j]*lp[jp] + lp[4+j]*lp[4+jp]
                      + lp[8+j]*lp[8+jp] + lp[12+j]*lp[12+jp];
                p++;
            }
    }
    if (STORE_QS && kh == 0){
        *(float4*)&qs_s[m*12+0] = make_float4(QS[0],QS[1],QS[2],QS[3]);
        *(float4*)&qs_s[m*12+4] = make_float4(QS[4],QS[5],QS[6],QS[7]);
        *(float2*)&qs_s[m*12+8] = make_float2(QS[8],QS[9]);
    }
    float invs[10];
    float rd = 0.f;
    const int cl = m >> 6;
    const float* base = &mw_s[(cl*NK + kh*10)*ROW];
    #pragma unroll
    for (int i=0;i<10;i++){
        const float* row = base + i*ROW;
        float4 w0 = *(const float4*)&row[0];
        float4 w1 = *(const float4*)&row[4];
        float4 w2 = *(const float4*)&row[8];
        float4 w3 = *(const float4*)&row[12];
        float4 m0 = *(const float4*)&row[16];
        float4 m1 = *(const float4*)&row[20];
        float2 m2 = *(const float2*)&row[24];
        float rn = row[26];
        rn += m0.x*QS[0] + m0.y*QS[1] + m0.z*QS[2] + m0.w*QS[3]
            + m1.x*QS[4] + m1.y*QS[5] + m1.z*QS[6] + m1.w*QS[7]
            + m2.x*QS[8] + m2.y*QS[9];
        rn += w0.x*lp[0] + w0.y*lp[1] + w0.z*lp[2] + w0.w*lp[3]
            + w1.x*lp[4] + w1.y*lp[5] + w1.z*lp[6] + w1.w*lp[7]
            + w2.x*lp[8] + w2.y*lp[9] + w2.z*lp[10]+ w2.w*lp[11]
            + w3.x*lp[12]+ w3.y*lp[13]+ w3.z*lp[14]+ w3.w*lp[15];
        float inv = frcp(rn);
        invs[i] = inv;
        rd += inv;
    }
    rd += __shfl_xor(rd, 1, 64);
    float ird = frcp(rd);
    #pragma unroll
    for (int i=0;i<10;i++){
        float t = invs[i]*ird;
        r_s[(kh*10+i)*RST + m] = t*t;
    }
}

__device__ __forceinline__ void reduce_g(const float* __restrict__ P, int n,
                                         float* tmp_s, float* g_s, int tid)
{
    for (int t = tid; t < NK*17; t += 256){
        int k = t/17, x = t%17;
        float acc = 0.f;
        #pragma unroll
        for (int s=0;s<NSPLIT;s++) acc += P[((n*NSPLIT+s)*NK + k)*17 + x];
        tmp_s[t] = acc;
    }
    __syncthreads();
    for (int t = tid; t < NK*16; t += 256){
        int k = t>>4, d = t&15;
        g_s[t] = tmp_s[k*17 + d] / tmp_s[k*17 + 16];
    }
}

// ---------------- routing iteration ----------------
template<int FIRST>
__global__ __launch_bounds__(256, 4)
void k_route(const float* __restrict__ l, const float* __restrict__ wgt,
             const float* __restrict__ g_in, const float* __restrict__ Pprev,
             float* __restrict__ Pout)
{
    const int split = blockIdx.x, n = blockIdx.y, tid = threadIdx.x;
    const int c0 = split*CPB;

    __shared__ float lp_s[CPB*64*LPST];    // 2560
    __shared__ float mw_s[CPB*NK*MWR_R];   // 1120
    __shared__ float wt_s[NK*33];          // 660
    __shared__ float r_s[NK*RST];          // 2640
    __shared__ float red_s[4*NK*17];       // 1360
    __shared__ float g_s[NK*16];
    __shared__ float tmp_s[NK*17];

    for (int t = tid; t < NK*32; t += 256){
        int k = t>>5, rest = t&31;
        wt_s[k*33 + rest] = wgt[k*512 + c0*16 + rest];
    }
    const float* lsrc = l + ((size_t)n*32 + c0)*1024;
    #pragma unroll
    for (int i=0;i<8;i++){
        int t = i*256 + tid;
        int cl = t>>10, dd = (t>>6)&15, wh = t&63;
        lp_s[(cl*64 + wh)*LPST + dd] = lsrc[t];
    }
    if (FIRST){
        for (int t=tid;t<NK*16;t+=256) g_s[t] = g_in[n*NK*16 + t];
        __syncthreads();
    } else {
        reduce_g(Pprev, n, tmp_s, g_s, tid);
        __syncthreads();
    }
    build_mw<MWR_R,0>(mw_s, wt_s, g_s, nullptr, tid);
    __syncthreads();
    phase1<MWR_R,0>(lp_s, mw_s, r_s, nullptr, tid);
    __syncthreads();

    // ---- phase 3: T[w,k,ij] = sum_m r*lp over this wave-pair's 32 m ----
    const int k3 = tid & 31, mi = tid >> 5;
    const int kk = (k3 < NK)? k3 : k3 - NK;    // alias rows for idle lanes
    const int mbase = mi*16;
    float T[16]; float sacc = 0.f;
    #pragma unroll
    for (int d=0;d<16;d++) T[d]=0.f;

    auto acc_m = [&](float r, int m){
        const float* lr = &lp_s[m*LPST];
        float4 v0 = *(const float4*)&lr[0];
        float4 v1 = *(const float4*)&lr[4];
        float4 v2 = *(const float4*)&lr[8];
        float4 v3 = *(const float4*)&lr[12];
        T[0]+=r*v0.x; T[1]+=r*v0.y; T[2]+=r*v0.z; T[3]+=r*v0.w;
        T[4]+=r*v1.x; T[5]+=r*v1.y; T[6]+=r*v1.z; T[7]+=r*v1.w;
        T[8]+=r*v2.x; T[9]+=r*v2.y; T[10]+=r*v2.z; T[11]+=r*v2.w;
        T[12]+=r*v3.x; T[13]+=r*v3.y; T[14]+=r*v3.z; T[15]+=r*v3.w;
        sacc += r;
    };
    #pragma unroll
    for (int j4=0;j4<4;j4++){
        float4 rv = *(const float4*)&r_s[kk*RST + mbase + j4*4];
        acc_m(rv.x, mbase + j4*4 + 0);
        acc_m(rv.y, mbase + j4*4 + 1);
        acc_m(rv.z, mbase + j4*4 + 2);
        acc_m(rv.w, mbase + j4*4 + 3);
    }
    #pragma unroll
    for (int d=0;d<16;d++) T[d] += __shfl_xor(T[d], 32, 64);
    sacc += __shfl_xor(sacc, 32, 64);
    if ((k3 < NK) && !(tid & 32)){
        float* row = &red_s[((tid>>6)*NK + k3)*17];
        #pragma unroll
        for (int d=0;d<16;d++) row[d] = T[d];
        row[16] = sacc;
    }
    __syncthreads();

    // ---- final: u[k,io] = sum_w sum_j T[w,k,ij] w[k,cl(w),j,o]; s ----
    for (int t = tid; t < NK*17; t += 256){
        int k = t/17, x = t%17;
        float acc = 0.f;
        if (x == 16){
            #pragma unroll
            for (int w=0;w<4;w++) acc += red_s[(w*NK+k)*17 + 16];
        } else {
            int i = x>>2, o = x&3;
            #pragma unroll
            for (int w=0;w<4;w++){
                int cl = w>>1;
                #pragma unroll
                for (int j=0;j<4;j++)
                    acc += red_s[(w*NK+k)*17 + i*4+j] * wt_s[k*33 + cl*16 + j*4+o];
            }
        }
        Pout[((n*NSPLIT+split)*NK + k)*17 + x] = acc;
    }
}

// ---------------- sigma pass ----------------
__global__ __launch_bounds__(256, 4)
void k_sigma(const float* __restrict__ l, const float* __restrict__ wgt,
             const float* __restrict__ P2, const float* __restrict__ P3,
             float* __restrict__ PS)
{
    const int split = blockIdx.x, n = blockIdx.y, tid = threadIdx.x;
    const int c0 = split*CPB;

    __shared__ float lp_s[CPB*64*LPST];    // 2560
    __shared__ float mw_s[CPB*NK*MWR_S];   // 1760
    __shared__ float wt_s[NK*33];          // 660
    __shared__ float r_s[NK*RST];          // 2640
    __shared__ float qs_s[128*12];         // 1536
    __shared__ float g2_s[NK*16], g3_s[NK*16];
    __shared__ float tmp_s[NK*17];
    __shared__ float is3_s[NK];
    __shared__ float red2_s[4*NK];

    for (int t = tid; t < NK*32; t += 256){
        int k = t>>5, rest = t&31;
        wt_s[k*33 + rest] = wgt[k*512 + c0*16 + rest];
    }
    const float* lsrc = l + ((size_t)n*32 + c0)*1024;
    #pragma unroll
    for (int i=0;i<8;i++){
        int t = i*256 + tid;
        int cl = t>>10, dd = (t>>6)&15, wh = t&63;
        lp_s[(cl*64 + wh)*LPST + dd] = lsrc[t];
    }
    reduce_g(P2, n, tmp_s, g2_s, tid);
    __syncthreads();
    reduce_g(P3, n, tmp_s, g3_s, tid);
    if (tid < NK) is3_s[tid] = 1.f / tmp_s[tid*17 + 16];
    __syncthreads();
    build_mw<MWR_S,1>(mw_s, wt_s, g2_s, g3_s, tid);
    __syncthreads();
    phase1<MWR_S,1>(lp_s, mw_s, r_s, qs_s, tid);
    __syncthreads();

    // ---- phase 3: sig[k] = sum_m r * (c3 + M~.QS + wg3.lp) ----
    const int k3 = tid & 31, mi = tid >> 5;
    const int kk = (k3 < NK)? k3 : k3 - NK;
    const int cl3 = mi >> 2;
    const int mbase = mi*16;
    const float* row = &mw_s[(cl3*NK + kk)*MWR_S];
    float Mt[10], wg3[16], c3;
    {
        float4 a0 = *(const float4*)&row[16];
        float4 a1 = *(const float4*)&row[20];
        float2 a2 = *(const float2*)&row[24];
        Mt[0]=a0.x; Mt[1]=a0.y; Mt[2]=a0.z; Mt[3]=a0.w;
        Mt[4]=a1.x; Mt[5]=a1.y; Mt[6]=a1.z; Mt[7]=a1.w;
        Mt[8]=a2.x; Mt[9]=a2.y;
        #pragma unroll
        for (int q=0;q<4;q++){
            float4 v = *(const float4*)&row[28 + q*4];
            wg3[q*4+0]=v.x; wg3[q*4+1]=v.y; wg3[q*4+2]=v.z; wg3[q*4+3]=v.w;
        }
        c3 = row[27];
    }
    float sig = 0.f;
    auto acc_sig = [&](float r, int m){
        const float* qsr = &qs_s[m*12];
        float4 q0 = *(const float4*)&qsr[0];
        float4 q1 = *(const float4*)&qsr[4];
        float2 q2 = *(const float2*)&qsr[8];
        float rn = c3;
        rn += Mt[0]*q0.x + Mt[1]*q0.y + Mt[2]*q0.z + Mt[3]*q0.w
            + Mt[4]*q1.x + Mt[5]*q1.y + Mt[6]*q1.z + Mt[7]*q1.w
            + Mt[8]*q2.x + Mt[9]*q2.y;
        const float* lr = &lp_s[m*LPST];
        float4 v0 = *(const float4*)&lr[0];
        float4 v1 = *(const float4*)&lr[4];
        float4 v2 = *(const float4*)&lr[8];
        float4 v3 = *(const float4*)&lr[12];
        rn += wg3[0]*v0.x + wg3[1]*v0.y + wg3[2]*v0.z + wg3[3]*v0.w
            + wg3[4]*v1.x + wg3[5]*v1.y + wg3[6]*v1.z + wg3[7]*v1.w
            + wg3[8]*v2.x + wg3[9]*v2.y + wg3[10]*v2.z + wg3[11]*v2.w
            + wg3[12]*v3.x + wg3[13]*v3.y + wg3[14]*v3.z + wg3[15]*v3.w;
        sig += r*rn;
    };
    #pragma unroll
    for (int j4=0;j4<4;j4++){
        float4 rv = *(const float4*)&r_s[kk*RST + mbase + j4*4];
        acc_sig(rv.x, mbase + j4*4 + 0);
        acc_sig(rv.y, mbase + j4*4 + 1);
        acc_sig(rv.z, mbase + j4*4 + 2);
        acc_sig(rv.w, mbase + j4*4 + 3);
    }
    sig += __shfl_xor(sig, 32, 64);
    if ((k3 < NK) && !(tid & 32)) red2_s[(tid>>6)*NK + k3] = sig;
    __syncthreads();
    if (tid < NK){
        float acc = red2_s[tid] + red2_s[NK+tid] + red2_s[2*NK+tid] + red2_s[3*NK+tid];
        PS[(n*NSPLIT+split)*NK + tid] = acc * is3_s[tid];
    }
}

// ---------------- finalize ----------------
__global__ __launch_bounds__(512)
void k_final(const float* __restrict__ P3, const float* __restrict__ PS,
             const float* __restrict__ beta, float* __restrict__ out)
{
    const int n = blockIdx.x, tid = threadIdx.x;
    __shared__ float tmp_s[NK*17];
    __shared__ float sig_s[NK];
    for (int t = tid; t < NK*17; t += 512){
        int k = t/17, x = t%17;
        float acc = 0.f;
        #pragma unroll
        for (int s=0;s<NSPLIT;s++) acc += P3[((n*NSPLIT+s)*NK + k)*17 + x];
        tmp_s[t] = acc;
    }
    if (tid < NK){
        float acc = 0.f;
        #pragma unroll
        for (int s=0;s<NSPLIT;s++) acc += PS[(n*NSPLIT+s)*NK + tid];
        sig_s[tid] = acc;
    }
    __syncthreads();
    if (tid < NK*16){
        int k = tid >> 4;
        out[1280 + n*320 + tid] = tmp_s[k*17 + (tid&15)] / tmp_s[k*17 + 16];
    }
    if (tid < NK){
        float z = beta[tid] - 0.5f*logf(sig_s[tid]);   // LAMBDA = 1
        out[n*NK + tid] = 1.f/(1.f + expf(-z));
    }
}

extern "C" void kernel_launch(void* const* d_in, const int* in_sizes, int n_in,
                              void* d_out, int out_size, void* d_ws, size_t ws_size,
                              hipStream_t stream)
{
    const float* l    = (const float*)d_in[0];
    const float* g    = (const float*)d_in[1];
    const float* wgt  = (const float*)d_in[2];
    const float* beta = (const float*)d_in[3];
    float* out = (float*)d_out;

    const size_t PSZ = (size_t)NB * NSPLIT * NK * 17;   // 348160 floats
    float* PA = (float*)d_ws;          // P1, then P3 (ping-pong)
    float* PB = PA + PSZ;              // P2
    float* PS = PB + PSZ;              // 64*16*20 floats

    dim3 grid(NSPLIT, NB), blk(256);
    k_route<1><<<grid, blk, 0, stream>>>(l, wgt, g, nullptr, PA);
    k_route<0><<<grid, blk, 0, stream>>>(l, wgt, nullptr, PA, PB);
    k_route<0><<<grid, blk, 0, stream>>>(l, wgt, nullptr, PB, PA);
    k_sigma<<<grid, blk, 0, stream>>>(l, wgt, PB, PA, PS);
    k_final<<<NB, 512, 0, stream>>>(PA, PS, beta, out);
}